// Round 11
// baseline (614.016 us; speedup 1.0000x reference)
//
#include <hip/hip_runtime.h>
#include <hip/hip_cooperative_groups.h>
#include <hip/hip_bf16.h>

namespace cg = cooperative_groups;

#define N_NODES 16384
#define N_EDGES 65536
#define NB      32
#define H       64
#define NLAYERS 3
#define NEG     0.1f
#define LN_EPS  1e-5f
#define HS_STRIDE 76   // u16; 152 B rows -> 2-way LDS banks (free)

typedef _Float16 f16;
typedef _Float16 f16x2 __attribute__((ext_vector_type(2)));
typedef _Float16 f16x8 __attribute__((ext_vector_type(8)));
typedef __fp16   hf16x2 __attribute__((ext_vector_type(2)));
typedef float    f32x16 __attribute__((ext_vector_type(16)));

union F16x8 { f16x8 v; f16x2 p[4]; int4 i4; int2 i2[2]; };
union F16x2U { f16x2 h2; hf16x2 raw; unsigned int u; };
union F16U   { f16 h; unsigned short u; };

__device__ __forceinline__ f16x2 pkrtz(float a, float b) {
    F16x2U t; t.raw = __builtin_amdgcn_cvt_pkrtz(a, b); return t.h2;
}
__device__ __forceinline__ float leaky(float v) { return v > 0.f ? v : NEG * v; }

struct Params {
    const float* x; const int* eidx; const float* ea; const int* bat;
    const float* Win; const float* bin;
    const float* ew1; const float* eb1; const float* ew2; const float* eb2;
    const float* ew3; const float* eb3;
    const float* rw;  const float* rb;  const float* lg;  const float* lb;
    const float* pw1; const float* pb1; const float* pw2; const float* pb2;
    const float* pw3; const float* pb3;
    float* out; float* ws;
};

struct MsgSmem {
    unsigned short hsL[128 * HS_STRIDE];  // 19456 B
    unsigned short e1L[128 * 72];         // 18432 B
    unsigned short e2L[128 * 72];         // 18432 B
    float eas[128 * 8];                   // 4096 B
    int dstL[128];                        // 512 B
};
struct NodeSmem {
    unsigned short hA[64 * 72];
    float outL[64][68];
};
struct HeadSmem {
    float cntL[32];
    float ps[32][64];
    float p1[32][64];
    float p2[32][32];
};
union __align__(16) AllSmem { MsgSmem m; NodeSmem n; HeadSmem hd; };  // 60928 B

// ---- B-fragment register loads (slot = i*8 + ks*2 + oq; i=c*2+di; i==64 bias)
__device__ __forceinline__ void loadB8(const f16* __restrict__ Bp, int c, int oq, int lane, F16x8* dstB) {
    const f16* base = Bp + (((size_t)(c * 16 + oq)) << 9) + lane * 8;
#pragma unroll
    for (int di = 0; di < 2; di++)
#pragma unroll
        for (int ks = 0; ks < 4; ks++)
            dstB[di * 4 + ks].i4 = *(const int4*)(base + ((di * 8 + ks * 2) << 9));
}
__device__ __forceinline__ void loadB4(const f16* __restrict__ Bp, int oq, int lane, F16x8* dstB) {
    const f16* base = Bp + (((size_t)(512 + oq)) << 9) + lane * 8;
#pragma unroll
    for (int ks = 0; ks < 4; ks++)
        dstB[ks].i4 = *(const int4*)(base + ((ks * 2) << 9));
}

__device__ __forceinline__ void msg_chunk2(int c, const F16x8* __restrict__ B,
                                           const unsigned short* hp0,
                                           const unsigned short* hp1,
                                           const f16x2 (*e2p)[4][4], f32x16* CC) {
    unsigned int rr0 = *(const unsigned int*)(hp0 + 2 * c);
    unsigned int rr1 = *(const unsigned int*)(hp1 + 2 * c);
    F16x2U h00, h01, h10, h11;
    h00.u = __builtin_amdgcn_perm(rr0, rr0, 0x01000100u);
    h10.u = __builtin_amdgcn_perm(rr0, rr0, 0x03020302u);
    h01.u = __builtin_amdgcn_perm(rr1, rr1, 0x01000100u);
    h11.u = __builtin_amdgcn_perm(rr1, rr1, 0x03020302u);
#pragma unroll
    for (int ks = 0; ks < 4; ks++) {
        F16x8 A00, A01, A10, A11;
#pragma unroll
        for (int r = 0; r < 4; r++) {
            A00.p[r] = h00.h2 * e2p[0][ks][r];
            A01.p[r] = h01.h2 * e2p[1][ks][r];
            A10.p[r] = h10.h2 * e2p[0][ks][r];
            A11.p[r] = h11.h2 * e2p[1][ks][r];
        }
        CC[0] = __builtin_amdgcn_mfma_f32_32x32x16_f16(A00.v, B[0 * 4 + ks].v, CC[0], 0, 0, 0);
        CC[1] = __builtin_amdgcn_mfma_f32_32x32x16_f16(A01.v, B[0 * 4 + ks].v, CC[1], 0, 0, 0);
        CC[2] = __builtin_amdgcn_mfma_f32_32x32x16_f16(A10.v, B[1 * 4 + ks].v, CC[2], 0, 0, 0);
        CC[3] = __builtin_amdgcn_mfma_f32_32x32x16_f16(A11.v, B[1 * 4 + ks].v, CC[3], 0, 0, 0);
    }
}

// ================================================================ phase bodies
__device__ __forceinline__ void msg_body(MsgSmem& S, const float* __restrict__ h,
        const float* __restrict__ ea,
        const float* __restrict__ w1, const float* __restrict__ b1,
        const float* __restrict__ w2, const float* __restrict__ b2,
        const f16* __restrict__ Bpl,
        const int* __restrict__ srcp, const int* __restrict__ dstp,
        float* __restrict__ agg_l, int eb, int t) {
    const int lane = t & 63;
    const int w    = t >> 6;
    const int eh   = w >> 1, oq = w & 1;
    const int m    = lane & 31;
    const int kp   = lane >> 5;

    for (int idx = t; idx < 640; idx += 256) {
        int r = idx / 5, d = idx - r * 5;
        S.eas[r * 8 + d] = ea[(size_t)eb * 5 + idx];
    }
    {
        int e    = t >> 1;
        int half = t & 1;
        int nsrc = srcp[eb + e];
        const float4* hr = (const float4*)(h + (size_t)nsrc * 64 + half * 32);
        unsigned int* hrow = (unsigned int*)S.hsL + e * (HS_STRIDE / 2) + half * 16;
#pragma unroll
        for (int q = 0; q < 8; q++) {
            float4 v = hr[q];
            F16x2U p0, p1;
            p0.raw = __builtin_amdgcn_cvt_pkrtz(v.x, v.y);
            p1.raw = __builtin_amdgcn_cvt_pkrtz(v.z, v.w);
            hrow[q * 2 + 0] = p0.u;
            hrow[q * 2 + 1] = p1.u;
        }
        if (t < 128) S.dstL[t] = dstp[eb + t];
    }
    __syncthreads();

    // edge-MLP stage 1
    {
        int kk = t & 63;
        int eg = t >> 6;
        float w1r[5];
#pragma unroll
        for (int d = 0; d < 5; d++) w1r[d] = w1[kk * 5 + d];
        float b1r = b1[kk];
#pragma unroll 4
        for (int g = 0; g < 32; g++) {
            int row = eg * 32 + g;
            float4 a4 = *(const float4*)(S.eas + row * 8);
            float a5 = S.eas[row * 8 + 4];
            float v = b1r + a4.x * w1r[0] + a4.y * w1r[1] + a4.z * w1r[2] + a4.w * w1r[3] + a5 * w1r[4];
            F16U z; z.h = (f16)leaky(v);
            S.e1L[row * 72 + kk] = z.u;
        }
    }
    __syncthreads();

    // edge-MLP stage 2 (MFMA)
    {
        F16x8 W2f[4];
#pragma unroll
        for (int ks = 0; ks < 4; ks++) {
            const float* s = w2 + (size_t)(oq * 32 + m) * 64 + ks * 16 + kp * 8;
            float4 a = ((const float4*)s)[0];
            float4 b = ((const float4*)s)[1];
            W2f[ks].p[0] = pkrtz(a.x, a.y);
            W2f[ks].p[1] = pkrtz(a.z, a.w);
            W2f[ks].p[2] = pkrtz(b.x, b.y);
            W2f[ks].p[3] = pkrtz(b.z, b.w);
        }
        float b2r = b2[oq * 32 + m];
#pragma unroll
        for (int tt = 0; tt < 2; tt++) {
            f32x16 C2 = {0,0,0,0,0,0,0,0,0,0,0,0,0,0,0,0};
#pragma unroll
            for (int ks = 0; ks < 4; ks++) {
                F16x8 A;
                A.i4 = *(const int4*)(S.e1L + (size_t)((eh * 2 + tt) * 32 + m) * 72 + ks * 16 + kp * 8);
                C2 = __builtin_amdgcn_mfma_f32_32x32x16_f16(A.v, W2f[ks].v, C2, 0, 0, 0);
            }
#pragma unroll
            for (int reg = 0; reg < 16; reg++) {
                int r = (reg & 3) + 8 * (reg >> 2) + 4 * kp;
                F16U z; z.h = (f16)leaky(C2[reg] + b2r);
                S.e2L[((eh * 2 + tt) * 32 + r) * 72 + oq * 32 + m] = z.u;
            }
        }
    }
    __syncthreads();

    f16x2 e2p[2][4][4];
#pragma unroll
    for (int tt = 0; tt < 2; tt++) {
#pragma unroll
        for (int ks = 0; ks < 4; ks++) {
            F16x8 q;
            q.i4 = *(const int4*)(S.e2L + (size_t)((eh * 2 + tt) * 32 + m) * 72 + ks * 16 + kp * 8);
            e2p[tt][ks][0] = q.p[0]; e2p[tt][ks][1] = q.p[1];
            e2p[tt][ks][2] = q.p[2]; e2p[tt][ks][3] = q.p[3];
        }
    }

    f32x16 CC[4];
#pragma unroll
    for (int q = 0; q < 4; q++)
#pragma unroll
        for (int r = 0; r < 16; r++) CC[q][r] = 0.f;

    const unsigned short* hp0 = S.hsL + ((eh * 2 + 0) * 32 + m) * HS_STRIDE;
    const unsigned short* hp1 = S.hsL + ((eh * 2 + 1) * 32 + m) * HS_STRIDE;

    F16x8 B0[8], B1[8];
    loadB8(Bpl, 0, oq, lane, B0);
    loadB8(Bpl, 1, oq, lane, B1);
    for (int it = 0; it < 15; it++) {
        int c = it * 2;
        msg_chunk2(c,     B0, hp0, hp1, e2p, CC);  loadB8(Bpl, c + 2, oq, lane, B0);
        msg_chunk2(c + 1, B1, hp0, hp1, e2p, CC);  loadB8(Bpl, c + 3, oq, lane, B1);
    }
    msg_chunk2(30, B0, hp0, hp1, e2p, CC);
    loadB4(Bpl, oq, lane, B0);
    msg_chunk2(31, B1, hp0, hp1, e2p, CC);
#pragma unroll
    for (int ks = 0; ks < 4; ks++) {
        int koff = (ks * 16 + kp * 8) * 2;
        const char* r0p = (const char*)S.hsL + (size_t)((eh * 2 + 0) * 32 + m) * (HS_STRIDE * 2) + koff;
        const char* r1p = (const char*)S.hsL + (size_t)((eh * 2 + 1) * 32 + m) * (HS_STRIDE * 2) + koff;
        F16x8 A0, A1;
        A0.i2[0] = *(const int2*)(r0p); A0.i2[1] = *(const int2*)(r0p + 8);
        A1.i2[0] = *(const int2*)(r1p); A1.i2[1] = *(const int2*)(r1p + 8);
        CC[0] = __builtin_amdgcn_mfma_f32_32x32x16_f16(A0.v, B0[ks].v, CC[0], 0, 0, 0);
        CC[1] = __builtin_amdgcn_mfma_f32_32x32x16_f16(A1.v, B0[ks].v, CC[1], 0, 0, 0);
    }

    int o = oq * 32 + m;
#pragma unroll
    for (int reg = 0; reg < 16; reg++) {
        int r = (reg & 3) + 8 * (reg >> 2) + 4 * kp;
        atomicAdd(&agg_l[(size_t)S.dstL[(eh * 2 + 0) * 32 + r] * 64 + o], CC[0][reg] + CC[2][reg]);
    }
#pragma unroll
    for (int reg = 0; reg < 16; reg++) {
        int r = (reg & 3) + 8 * (reg >> 2) + 4 * kp;
        atomicAdd(&agg_l[(size_t)S.dstL[(eh * 2 + 1) * 32 + r] * 64 + o], CC[1][reg] + CC[3][reg]);
    }
}

__device__ __forceinline__ void node_body(NodeSmem& S, float* __restrict__ h,
        const float* __restrict__ agg_l, const float* __restrict__ deg,
        const float* __restrict__ rwl, const float* __restrict__ rbl,
        const float* __restrict__ lgl, const float* __restrict__ lbl,
        const int* __restrict__ bat, float* __restrict__ pooled,
        int last, int nb, int t) {
    const int lane = t & 63, w = t >> 6;
    const int nq = w >> 1, oq = w & 1;
    const int m = lane & 31, kp = lane >> 5;

    {
        int r = t >> 2, c0 = (t & 3) * 16;
        const float4* hr = (const float4*)(h + (size_t)(nb + r) * 64 + c0);
        unsigned int* drow = (unsigned int*)S.hA + r * 36 + c0 / 2;
#pragma unroll
        for (int q = 0; q < 4; q++) {
            float4 v = hr[q];
            F16x2U p0, p1;
            p0.raw = __builtin_amdgcn_cvt_pkrtz(v.x, v.y);
            p1.raw = __builtin_amdgcn_cvt_pkrtz(v.z, v.w);
            drow[q * 2] = p0.u; drow[q * 2 + 1] = p1.u;
        }
    }
    F16x8 Bf[4];
#pragma unroll
    for (int ks = 0; ks < 4; ks++) {
        const float* s = rwl + (size_t)(oq * 32 + m) * 64 + ks * 16 + kp * 8;
        float4 a = ((const float4*)s)[0];
        float4 b = ((const float4*)s)[1];
        Bf[ks].p[0] = pkrtz(a.x, a.y);
        Bf[ks].p[1] = pkrtz(a.z, a.w);
        Bf[ks].p[2] = pkrtz(b.x, b.y);
        Bf[ks].p[3] = pkrtz(b.z, b.w);
    }
    __syncthreads();

    f32x16 C = {0,0,0,0,0,0,0,0,0,0,0,0,0,0,0,0};
#pragma unroll
    for (int ks = 0; ks < 4; ks++) {
        F16x8 A;
        A.i4 = *(const int4*)(S.hA + (size_t)(nq * 32 + m) * 72 + ks * 16 + kp * 8);
        C = __builtin_amdgcn_mfma_f32_32x32x16_f16(A.v, Bf[ks].v, C, 0, 0, 0);
    }

    int o = oq * 32 + m;
#pragma unroll
    for (int reg = 0; reg < 16; reg++) {
        int r = (reg & 3) + 8 * (reg >> 2) + 4 * kp;
        int n = nq * 32 + r;
        S.outL[n][o] = C[reg] + rbl[o] + agg_l[(size_t)(nb + n) * 64 + o] / fmaxf(deg[nb + n], 1.0f);
    }
    __syncthreads();

    float gj = lgl[lane], bj = lbl[lane];
    float accp = 0.f;
    int cur = bat[nb + w * 16];
    for (int q = 0; q < 16; q++) {
        int n = w * 16 + q;
        float v = S.outL[n][lane];
        float mu = v;
#pragma unroll
        for (int msk = 32; msk > 0; msk >>= 1) mu += __shfl_xor(mu, msk);
        mu *= (1.f / 64.f);
        float d = v - mu;
        float var = d * d;
#pragma unroll
        for (int msk = 32; msk > 0; msk >>= 1) var += __shfl_xor(var, msk);
        var *= (1.f / 64.f);
        float ov = d * rsqrtf(var + LN_EPS) * gj + bj;
        float hn = leaky(ov) + h[(size_t)(nb + n) * 64 + lane];
        h[(size_t)(nb + n) * 64 + lane] = hn;
        if (last) {
            int b = bat[nb + n];
            if (b != cur) { atomicAdd(&pooled[cur * 64 + lane], accp); accp = 0.f; cur = b; }
            accp += hn;
        }
    }
    if (last) atomicAdd(&pooled[cur * 64 + lane], accp);
}

__device__ __forceinline__ void head_body(HeadSmem& S, const float* __restrict__ pooled,
        const int* __restrict__ bat,
        const float* pw1, const float* pb1, const float* pw2, const float* pb2,
        const float* pw3, const float* pb3, float* __restrict__ out, int t) {
    if (t < 32) S.cntL[t] = 0.f;
    __syncthreads();
    {
        const int4* bp4 = (const int4*)(bat + t * 64);
        int cur = bat[t * 64];
        float c = 0.f;
        for (int q = 0; q < 16; q++) {
            int4 b4 = bp4[q];
            int bs[4] = { b4.x, b4.y, b4.z, b4.w };
#pragma unroll
            for (int e = 0; e < 4; e++) {
                if (bs[e] != cur) { atomicAdd(&S.cntL[cur], c); cur = bs[e]; c = 0.f; }
                c += 1.f;
            }
        }
        atomicAdd(&S.cntL[cur], c);
    }
    __syncthreads();
    for (int idx = t; idx < 2048; idx += 256) {
        int b = idx >> 6, j = idx & 63;
        S.ps[b][j] = pooled[idx] / fmaxf(S.cntL[b], 1.0f);
    }
    __syncthreads();
    for (int idx = t; idx < 2048; idx += 256) {
        int b = idx >> 6, j = idx & 63;
        float v = pb1[j];
#pragma unroll 8
        for (int i = 0; i < 64; i++) v += S.ps[b][i] * pw1[j * 64 + i];
        S.p1[b][j] = leaky(v);
    }
    __syncthreads();
    for (int idx = t; idx < 1024; idx += 256) {
        int b = idx >> 5, j = idx & 31;
        float v = pb2[j];
#pragma unroll 8
        for (int i = 0; i < 64; i++) v += S.p1[b][i] * pw2[j * 64 + i];
        S.p2[b][j] = leaky(v);
    }
    __syncthreads();
    if (t < 32) {
        float v = pb3[0];
#pragma unroll 8
        for (int i = 0; i < 32; i++) v += S.p2[t][i] * pw3[i];
        out[t] = v;
    }
}

// ================================================================ cooperative mega-kernel (grid 256, 1 block/CU)
__global__ __launch_bounds__(256, 1) void k_all(Params P) {
    __shared__ AllSmem smem;
    cg::grid_group grid = cg::this_grid();

    const int t    = threadIdx.x;
    const int bid  = blockIdx.x;
    const int lane = t & 63;
    const int w    = t >> 6;
    const int m    = lane & 31;
    const int kp   = lane >> 5;

    float* ws     = P.ws;
    float* h      = ws;
    float* agg    = ws + 1048576;
    float* deg    = ws + 4194304;
    float* pooled = ws + 4210688;
    f16*   Bp     = (f16*)(ws + 4212800);
    const int* srcp = P.eidx;
    const int* dstp = P.eidx + N_EDGES;

    // phase Z: zero agg[3] + deg + pooled
    {
        float4* z = (float4*)(ws + 1048576);
        for (int i = bid * 256 + t; i < 791056; i += 256 * 256)
            z[i] = make_float4(0.f, 0.f, 0.f, 0.f);
    }
    grid.sync();

    // phase S: inproj + degree + Bp prep
    {
        int base = bid * 4096;
#pragma unroll
        for (int q = 0; q < 16; q++) {
            int idx = base + q * 256 + t;
            int n = idx >> 6, j = idx & 63;
            const float* xr = P.x + n * 4;
            const float* wr = P.Win + j * 4;
            float v = P.bin[j] + xr[0] * wr[0] + xr[1] * wr[1] + xr[2] * wr[2] + xr[3] * wr[3];
            h[idx] = leaky(v);
        }
        atomicAdd(&deg[dstp[bid * 256 + t]], 1.0f);
        for (int gslot = bid * 4 + w; gslot < 1560; gslot += 1024) {
            int l     = gslot / 520;
            int slot  = gslot - l * 520;
            const float* ew3l = P.ew3 + (size_t)l * 262144;
            const float* eb3l = P.eb3 + (size_t)l * 4096;
            int i   = slot >> 3;
            int rem = slot & 7;
            int ks  = rem >> 1;
            int oq  = rem & 1;
            int o   = oq * 32 + m;
            int k0  = ks * 16 + kp * 8;
            float v[8];
            if (i < 64) {
                const float* s = ew3l + ((size_t)(i * 64 + o)) * 64 + k0;
                float4 a = ((const float4*)s)[0];
                float4 b = ((const float4*)s)[1];
                v[0] = a.x; v[1] = a.y; v[2] = a.z; v[3] = a.w;
                v[4] = b.x; v[5] = b.y; v[6] = b.z; v[7] = b.w;
            } else {
#pragma unroll
                for (int j = 0; j < 8; j++) v[j] = eb3l[(k0 + j) * 64 + o];
            }
            union { int4 i4; f16 a[8]; } outw;
#pragma unroll
            for (int j = 0; j < 8; j++) outw.a[j] = (f16)v[j];
            *(int4*)(Bp + (size_t)l * 266240 + (size_t)slot * 512 + lane * 8) = outw.i4;
        }
    }
    grid.sync();

    for (int l = 0; l < NLAYERS; l++) {
        float* agg_l = agg + (size_t)l * 1048576;
        // msg phase: 2 edge-groups per block
#pragma unroll 1
        for (int g = 0; g < 2; g++) {
            if (g) __syncthreads();
            msg_body(smem.m, h, P.ea, P.ew1 + l * 320, P.eb1 + l * 64,
                     P.ew2 + l * 4096, P.eb2 + l * 64,
                     Bp + (size_t)l * 266240, srcp, dstp, agg_l,
                     (g * 256 + bid) * 128, t);
        }
        grid.sync();
        // node phase
        node_body(smem.n, h, agg_l, deg, P.rw + l * 4096, P.rb + l * 64,
                  P.lg + l * 64, P.lb + l * 64, P.bat, pooled,
                  (l == NLAYERS - 1) ? 1 : 0, bid * 64, t);
        grid.sync();
    }

    if (bid == 0)
        head_body(smem.hd, pooled, P.bat, P.pw1, P.pb1, P.pw2, P.pb2, P.pw3, P.pb3, P.out, t);
}

// ================================================================ fallback kernels (R9 path)
__global__ __launch_bounds__(256) void k_setup(const float* __restrict__ x,
                                               const float* __restrict__ Win,
                                               const float* __restrict__ bin,
                                               const int* __restrict__ dst,
                                               const float* __restrict__ ew3,
                                               const float* __restrict__ eb3,
                                               float* __restrict__ h,
                                               float* __restrict__ deg,
                                               f16* __restrict__ Bp) {
    int bid = blockIdx.x;
    if (bid < 4096) {
        int t = bid * 256 + threadIdx.x;
        int n = t >> 6, j = t & 63;
        const float* xr = x + n * 4;
        const float* wr = Win + j * 4;
        float v = bin[j] + xr[0] * wr[0] + xr[1] * wr[1] + xr[2] * wr[2] + xr[3] * wr[3];
        h[t] = leaky(v);
    } else if (bid < 4352) {
        int e = (bid - 4096) * 256 + threadIdx.x;
        atomicAdd(&deg[dst[e]], 1.0f);
    } else {
        int tg    = (bid - 4352) * 256 + threadIdx.x;
        int lane  = tg & 63;
        int gslot = tg >> 6;
        int l     = gslot / 520;
        int slot  = gslot - l * 520;
        const float* ew3l = ew3 + (size_t)l * 262144;
        const float* eb3l = eb3 + (size_t)l * 4096;
        int i   = slot >> 3;
        int rem = slot & 7;
        int ks  = rem >> 1;
        int oq  = rem & 1;
        int o   = oq * 32 + (lane & 31);
        int k0  = ks * 16 + (lane >> 5) * 8;
        float v[8];
        if (i < 64) {
            const float* s = ew3l + ((size_t)(i * 64 + o)) * 64 + k0;
            float4 a = ((const float4*)s)[0];
            float4 b = ((const float4*)s)[1];
            v[0] = a.x; v[1] = a.y; v[2] = a.z; v[3] = a.w;
            v[4] = b.x; v[5] = b.y; v[6] = b.z; v[7] = b.w;
        } else {
#pragma unroll
            for (int j = 0; j < 8; j++) v[j] = eb3l[(k0 + j) * 64 + o];
        }
        union { int4 i4; f16 a[8]; } outw;
#pragma unroll
        for (int j = 0; j < 8; j++) outw.a[j] = (f16)v[j];
        *(int4*)(Bp + (size_t)l * 266240 + (size_t)slot * 512 + lane * 8) = outw.i4;
    }
}

__global__ __launch_bounds__(256, 2) void k_msg_s(const float* __restrict__ h,
                                                  const float* __restrict__ ea,
                                                  const float* __restrict__ w1,
                                                  const float* __restrict__ b1,
                                                  const float* __restrict__ w2,
                                                  const float* __restrict__ b2,
                                                  const f16* __restrict__ Bp,
                                                  const int* __restrict__ src,
                                                  const int* __restrict__ dst,
                                                  float* __restrict__ agg) {
    __shared__ MsgSmem S;
    msg_body(S, h, ea, w1, b1, w2, b2, Bp, src, dst, agg, blockIdx.x * 128, threadIdx.x);
}

__global__ __launch_bounds__(256) void k_node_s(const float* __restrict__ agg,
                                                const float* __restrict__ deg,
                                                const float* __restrict__ rw,
                                                const float* __restrict__ rb,
                                                const float* __restrict__ lg,
                                                const float* __restrict__ lb,
                                                float* __restrict__ h,
                                                const int* __restrict__ batch,
                                                float* __restrict__ pooled,
                                                int last) {
    __shared__ NodeSmem S;
    node_body(S, h, agg, deg, rw, rb, lg, lb, batch, pooled, last, blockIdx.x * 64, threadIdx.x);
}

__global__ __launch_bounds__(256) void k_head_s(const float* __restrict__ pooled,
                                                const int* __restrict__ batch,
                                                const float* __restrict__ pw1, const float* __restrict__ pb1,
                                                const float* __restrict__ pw2, const float* __restrict__ pb2,
                                                const float* __restrict__ pw3, const float* __restrict__ pb3,
                                                float* __restrict__ out) {
    __shared__ HeadSmem S;
    head_body(S, pooled, batch, pw1, pb1, pw2, pb2, pw3, pb3, out, threadIdx.x);
}

// ----------------------------------------------------------------
extern "C" void kernel_launch(void* const* d_in, const int* in_sizes, int n_in,
                              void* d_out, int out_size, void* d_ws, size_t ws_size,
                              hipStream_t stream) {
    Params hp;
    hp.x    = (const float*)d_in[0];
    hp.eidx = (const int*)  d_in[1];
    hp.ea   = (const float*)d_in[2];
    hp.bat  = (const int*)  d_in[3];
    hp.Win  = (const float*)d_in[4];
    hp.bin  = (const float*)d_in[5];
    hp.ew1  = (const float*)d_in[6];
    hp.eb1  = (const float*)d_in[7];
    hp.ew2  = (const float*)d_in[8];
    hp.eb2  = (const float*)d_in[9];
    hp.ew3  = (const float*)d_in[10];
    hp.eb3  = (const float*)d_in[11];
    hp.rw   = (const float*)d_in[12];
    hp.rb   = (const float*)d_in[13];
    hp.lg   = (const float*)d_in[14];
    hp.lb   = (const float*)d_in[15];
    hp.pw1  = (const float*)d_in[16];
    hp.pb1  = (const float*)d_in[17];
    hp.pw2  = (const float*)d_in[18];
    hp.pb2  = (const float*)d_in[19];
    hp.pw3  = (const float*)d_in[20];
    hp.pb3  = (const float*)d_in[21];
    hp.out  = (float*)d_out;
    hp.ws   = (float*)d_ws;

    void* args[] = { (void*)&hp };
    hipError_t err = hipLaunchCooperativeKernel(reinterpret_cast<void*>(k_all),
                                                dim3(256), dim3(256), args, 0, stream);
    if (err != hipSuccess) {
        // fallback: proven R9 multi-dispatch path (bit-identical math)
        float* ws     = (float*)d_ws;
        float* h      = ws;
        float* agg    = ws + 1048576;
        float* deg    = ws + 4194304;
        float* pooled = ws + 4210688;
        f16*   Bp     = (f16*)(ws + 4212800);
        const int* srcp = (const int*)d_in[1];
        const int* dstp = srcp + N_EDGES;

        (void)hipMemsetAsync(agg, 0, (size_t)3164224 * sizeof(float), stream);
        k_setup<<<4742, 256, 0, stream>>>(hp.x, hp.Win, hp.bin, dstp, hp.ew3, hp.eb3, h, deg, Bp);
        for (int l = 0; l < NLAYERS; l++) {
            float* agg_l = agg + (size_t)l * 1048576;
            k_msg_s <<<N_EDGES / 128, 256, 0, stream>>>(h, hp.ea, hp.ew1 + l * 320, hp.eb1 + l * 64,
                                                        hp.ew2 + l * 4096, hp.eb2 + l * 64,
                                                        Bp + (size_t)l * 266240, srcp, dstp, agg_l);
            k_node_s<<<N_NODES / 64, 256, 0, stream>>>(agg_l, deg, hp.rw + l * 4096, hp.rb + l * 64,
                                                       hp.lg + l * 64, hp.lb + l * 64, h,
                                                       hp.bat, pooled, l == NLAYERS - 1 ? 1 : 0);
        }
        k_head_s<<<1, 256, 0, stream>>>(pooled, hp.bat, hp.pw1, hp.pb1, hp.pw2, hp.pb2,
                                        hp.pw3, hp.pb3, (float*)d_out);
    }
}

// Round 12
// 545.436 us; speedup vs baseline: 1.1257x; 1.1257x over previous
//
#include <hip/hip_runtime.h>
#include <hip/hip_cooperative_groups.h>
#include <hip/hip_bf16.h>

namespace cg = cooperative_groups;

#define N_NODES 16384
#define N_EDGES 65536
#define NB      32
#define H       64
#define NLAYERS 3
#define NEG     0.1f
#define LN_EPS  1e-5f
#define HS_STRIDE 76   // u16; 152 B rows -> 2-way LDS banks (free)

typedef _Float16 f16;
typedef _Float16 f16x2 __attribute__((ext_vector_type(2)));
typedef _Float16 f16x8 __attribute__((ext_vector_type(8)));
typedef __fp16   hf16x2 __attribute__((ext_vector_type(2)));
typedef float    f32x16 __attribute__((ext_vector_type(16)));

union F16x8 { f16x8 v; f16x2 p[4]; int4 i4; int2 i2[2]; f16 e[8]; };
union F16x2U { f16x2 h2; hf16x2 raw; unsigned int u; };
union F16U   { f16 h; unsigned short u; };

__device__ __forceinline__ f16x2 pkrtz(float a, float b) {
    F16x2U t; t.raw = __builtin_amdgcn_cvt_pkrtz(a, b); return t.h2;
}
__device__ __forceinline__ float leaky(float v) { return v > 0.f ? v : NEG * v; }

struct Params {
    const float* x; const int* eidx; const float* ea; const int* bat;
    const float* Win; const float* bin;
    const float* ew1; const float* eb1; const float* ew2; const float* eb2;
    const float* ew3; const float* eb3;
    const float* rw;  const float* rb;  const float* lg;  const float* lb;
    const float* pw1; const float* pb1; const float* pw2; const float* pb2;
    const float* pw3; const float* pb3;
    float* out; float* ws;
};

struct MsgSmem {
    unsigned short hsL[256 * HS_STRIDE];  // 38912 B
    unsigned short e2L[128 * 72];         // 18432 B (per-half, reused)
    int dstL[256];                        // 1024 B
};                                        // 58368 B
struct NodeSmem {
    unsigned short hA[64 * 72];
    float outL[64][68];
};
struct HeadSmem {
    float cntL[32];
    float ps[32][64];
    float p1[32][64];
    float p2[32][32];
};
union __align__(16) AllSmem { MsgSmem m; NodeSmem n; HeadSmem hd; };  // 58368 B

// ---- B-fragment register loads (slot = i*8 + ks*2 + oq; i=c*2+di; i==64 bias)
__device__ __forceinline__ void loadB8(const f16* __restrict__ Bp, int c, int oq, int lane, F16x8* dstB) {
    const f16* base = Bp + (((size_t)(c * 16 + oq)) << 9) + lane * 8;
#pragma unroll
    for (int di = 0; di < 2; di++)
#pragma unroll
        for (int ks = 0; ks < 4; ks++)
            dstB[di * 4 + ks].i4 = *(const int4*)(base + ((di * 8 + ks * 2) << 9));
}
__device__ __forceinline__ void loadB4(const f16* __restrict__ Bp, int oq, int lane, F16x8* dstB) {
    const f16* base = Bp + (((size_t)(512 + oq)) << 9) + lane * 8;
#pragma unroll
    for (int ks = 0; ks < 4; ks++)
        dstB[ks].i4 = *(const int4*)(base + ((ks * 2) << 9));
}

// one chunk (2 i-slots): 32 MFMA across 4 tile-chains (R7 shape, 1024-cyc coverage)
__device__ __forceinline__ void msg_chunk4(int c, const F16x8* __restrict__ B,
                                           const unsigned short* const* hp,
                                           const f16x2 (*e2p)[4][4], f32x16* C) {
    unsigned int rr[4];
#pragma unroll
    for (int tt = 0; tt < 4; tt++) rr[tt] = *(const unsigned int*)(hp[tt] + 2 * c);
#pragma unroll
    for (int di = 0; di < 2; di++) {
        unsigned int sel = di ? 0x03020302u : 0x01000100u;
        F16x2U hh[4];
#pragma unroll
        for (int tt = 0; tt < 4; tt++) hh[tt].u = __builtin_amdgcn_perm(rr[tt], rr[tt], sel);
#pragma unroll
        for (int ks = 0; ks < 4; ks++) {
#pragma unroll
            for (int tt = 0; tt < 4; tt++) {
                F16x8 A;
#pragma unroll
                for (int r = 0; r < 4; r++) A.p[r] = hh[tt].h2 * e2p[tt][ks][r];
                C[tt] = __builtin_amdgcn_mfma_f32_32x32x16_f16(A.v, B[di * 4 + ks].v, C[tt], 0, 0, 0);
            }
        }
    }
}

// ================================================================ msg body: 256 edges, 4 waves,
// wave (eh,oq) = 4 edge-tiles (eh*128..+127) x 32 outputs. Fused edge-MLP with
// e1 computed straight into A-fragment registers (no e1 LDS), e2 via one
// 128-edge LDS buffer reused across two half-passes.
__device__ __forceinline__ void msg_body(MsgSmem& S, const float* __restrict__ h,
        const float* __restrict__ ea,
        const float* __restrict__ w1, const float* __restrict__ b1,
        const float* __restrict__ w2, const float* __restrict__ b2,
        const f16* __restrict__ Bpl,
        const int* __restrict__ srcp, const int* __restrict__ dstp,
        float* __restrict__ agg_l, int eb, int t) {
    const int lane = t & 63;
    const int w    = t >> 6;
    const int eh   = w >> 1, oq = w & 1;
    const int m    = lane & 31;
    const int kp   = lane >> 5;

    // ---- prologue: stage all 256 h rows (gathered by src, fp32 -> f16); dst
    {
        int nsrc = srcp[eb + t];
        const float4* hr = (const float4*)(h + (size_t)nsrc * 64);
        unsigned int* hrow = (unsigned int*)S.hsL + t * (HS_STRIDE / 2);
#pragma unroll
        for (int q = 0; q < 16; q++) {
            float4 v = hr[q];
            F16x2U p0, p1;
            p0.raw = __builtin_amdgcn_cvt_pkrtz(v.x, v.y);
            p1.raw = __builtin_amdgcn_cvt_pkrtz(v.z, v.w);
            hrow[q * 2 + 0] = p0.u;
            hrow[q * 2 + 1] = p1.u;
        }
        S.dstL[t] = dstp[eb + t];
    }

    // ---- edge-MLP weights (once): W2f for both output halves; b2
    F16x8 W2f[2][4];
#pragma unroll
    for (int oh = 0; oh < 2; oh++)
#pragma unroll
        for (int ks = 0; ks < 4; ks++) {
            const float* s = w2 + (size_t)(oh * 32 + m) * 64 + ks * 16 + kp * 8;
            float4 a = ((const float4*)s)[0];
            float4 b = ((const float4*)s)[1];
            W2f[oh][ks].p[0] = pkrtz(a.x, a.y);
            W2f[oh][ks].p[1] = pkrtz(a.z, a.w);
            W2f[oh][ks].p[2] = pkrtz(b.x, b.y);
            W2f[oh][ks].p[3] = pkrtz(b.z, b.w);
        }
    float b2r0 = b2[m], b2r1 = b2[32 + m];

    f16x2 e2p[4][4][4];   // this wave's 4 K-loop tiles (filled when g == eh)

#pragma unroll 1
    for (int g = 0; g < 2; g++) {
        if (g) __syncthreads();   // protect e2L reuse (prev half's readers done)

        // ---- stage 1 in registers: wave w owns half-local tile w (32 edges)
        // lane (m,kp) computes e1[edge m][kk = ks*16+kp*8+j] == its A-fragments
        F16x8 A1[4];
        {
            int edge = eb + g * 128 + w * 32 + m;
            const float* ar = ea + (size_t)edge * 5;
            float a0 = ar[0], a1 = ar[1], a2 = ar[2], a3 = ar[3], a4 = ar[4];
#pragma unroll
            for (int ks = 0; ks < 4; ks++) {
#pragma unroll
                for (int j = 0; j < 8; j++) {
                    int kk = ks * 16 + kp * 8 + j;
                    const float* wr = w1 + kk * 5;
                    float v = b1[kk] + a0 * wr[0] + a1 * wr[1] + a2 * wr[2] + a3 * wr[3] + a4 * wr[4];
                    A1[ks].e[j] = (f16)leaky(v);
                }
            }
        }
        // ---- stage 2 MFMA: e2 tile (32 edges x 64 out) for half-local tile w
        {
            f32x16 C20 = {0,0,0,0,0,0,0,0,0,0,0,0,0,0,0,0};
            f32x16 C21 = {0,0,0,0,0,0,0,0,0,0,0,0,0,0,0,0};
#pragma unroll
            for (int ks = 0; ks < 4; ks++) {
                C20 = __builtin_amdgcn_mfma_f32_32x32x16_f16(A1[ks].v, W2f[0][ks].v, C20, 0, 0, 0);
                C21 = __builtin_amdgcn_mfma_f32_32x32x16_f16(A1[ks].v, W2f[1][ks].v, C21, 0, 0, 0);
            }
#pragma unroll
            for (int reg = 0; reg < 16; reg++) {
                int r = (reg & 3) + 8 * (reg >> 2) + 4 * kp;
                F16U z0; z0.h = (f16)leaky(C20[reg] + b2r0);
                F16U z1; z1.h = (f16)leaky(C21[reg] + b2r1);
                S.e2L[(w * 32 + r) * 72 + m]      = z0.u;
                S.e2L[(w * 32 + r) * 72 + 32 + m] = z1.u;
            }
        }
        __syncthreads();
        // ---- owning waves (eh == g) pick up their A-operand e2 fragments
        if (eh == g) {
#pragma unroll
            for (int tt = 0; tt < 4; tt++)
#pragma unroll
                for (int ks = 0; ks < 4; ks++) {
                    F16x8 q;
                    q.i4 = *(const int4*)(S.e2L + (size_t)(tt * 32 + m) * 72 + ks * 16 + kp * 8);
                    e2p[tt][ks][0] = q.p[0]; e2p[tt][ks][1] = q.p[1];
                    e2p[tt][ks][2] = q.p[2]; e2p[tt][ks][3] = q.p[3];
                }
        }
    }

    // ---- K-loop (R7 shape): 4 chains, static register dbuf, barrier-free
    f32x16 C[4];
#pragma unroll
    for (int tt = 0; tt < 4; tt++)
#pragma unroll
        for (int r = 0; r < 16; r++) C[tt][r] = 0.f;

    const unsigned short* hp[4];
#pragma unroll
    for (int tt = 0; tt < 4; tt++)
        hp[tt] = S.hsL + ((eh * 4 + tt) * 32 + m) * HS_STRIDE;

    F16x8 B0[8], B1[8];
    loadB8(Bpl, 0, oq, lane, B0);
    loadB8(Bpl, 1, oq, lane, B1);
    for (int it = 0; it < 15; it++) {
        int c = it * 2;
        msg_chunk4(c,     B0, hp, e2p, C);  loadB8(Bpl, c + 2, oq, lane, B0);
        msg_chunk4(c + 1, B1, hp, e2p, C);  loadB8(Bpl, c + 3, oq, lane, B1);
    }
    msg_chunk4(30, B0, hp, e2p, C);
    loadB4(Bpl, oq, lane, B0);              // bias frags
    msg_chunk4(31, B1, hp, e2p, C);

    // ---- bias chunk: A = h itself (k plays the i role)
#pragma unroll
    for (int ks = 0; ks < 4; ks++) {
        int koff = (ks * 16 + kp * 8) * 2;
#pragma unroll
        for (int tt = 0; tt < 4; tt++) {
            const char* rp = (const char*)S.hsL + (size_t)((eh * 4 + tt) * 32 + m) * (HS_STRIDE * 2) + koff;
            F16x8 A;
            A.i2[0] = *(const int2*)(rp); A.i2[1] = *(const int2*)(rp + 8);
            C[tt] = __builtin_amdgcn_mfma_f32_32x32x16_f16(A.v, B0[ks].v, C[tt], 0, 0, 0);
        }
    }

    // ---- scatter epilogue
    int o = oq * 32 + m;
#pragma unroll
    for (int tt = 0; tt < 4; tt++) {
#pragma unroll
        for (int reg = 0; reg < 16; reg++) {
            int r = (reg & 3) + 8 * (reg >> 2) + 4 * kp;
            atomicAdd(&agg_l[(size_t)S.dstL[(eh * 4 + tt) * 32 + r] * 64 + o], C[tt][reg]);
        }
    }
}

// ================================================================ node / head bodies (R9-proven)
__device__ __forceinline__ void node_body(NodeSmem& S, float* __restrict__ h,
        const float* __restrict__ agg_l, const float* __restrict__ deg,
        const float* __restrict__ rwl, const float* __restrict__ rbl,
        const float* __restrict__ lgl, const float* __restrict__ lbl,
        const int* __restrict__ bat, float* __restrict__ pooled,
        int last, int nb, int t) {
    const int lane = t & 63, w = t >> 6;
    const int nq = w >> 1, oq = w & 1;
    const int m = lane & 31, kp = lane >> 5;

    {
        int r = t >> 2, c0 = (t & 3) * 16;
        const float4* hr = (const float4*)(h + (size_t)(nb + r) * 64 + c0);
        unsigned int* drow = (unsigned int*)S.hA + r * 36 + c0 / 2;
#pragma unroll
        for (int q = 0; q < 4; q++) {
            float4 v = hr[q];
            F16x2U p0, p1;
            p0.raw = __builtin_amdgcn_cvt_pkrtz(v.x, v.y);
            p1.raw = __builtin_amdgcn_cvt_pkrtz(v.z, v.w);
            drow[q * 2] = p0.u; drow[q * 2 + 1] = p1.u;
        }
    }
    F16x8 Bf[4];
#pragma unroll
    for (int ks = 0; ks < 4; ks++) {
        const float* s = rwl + (size_t)(oq * 32 + m) * 64 + ks * 16 + kp * 8;
        float4 a = ((const float4*)s)[0];
        float4 b = ((const float4*)s)[1];
        Bf[ks].p[0] = pkrtz(a.x, a.y);
        Bf[ks].p[1] = pkrtz(a.z, a.w);
        Bf[ks].p[2] = pkrtz(b.x, b.y);
        Bf[ks].p[3] = pkrtz(b.z, b.w);
    }
    __syncthreads();

    f32x16 C = {0,0,0,0,0,0,0,0,0,0,0,0,0,0,0,0};
#pragma unroll
    for (int ks = 0; ks < 4; ks++) {
        F16x8 A;
        A.i4 = *(const int4*)(S.hA + (size_t)(nq * 32 + m) * 72 + ks * 16 + kp * 8);
        C = __builtin_amdgcn_mfma_f32_32x32x16_f16(A.v, Bf[ks].v, C, 0, 0, 0);
    }

    int o = oq * 32 + m;
#pragma unroll
    for (int reg = 0; reg < 16; reg++) {
        int r = (reg & 3) + 8 * (reg >> 2) + 4 * kp;
        int n = nq * 32 + r;
        S.outL[n][o] = C[reg] + rbl[o] + agg_l[(size_t)(nb + n) * 64 + o] / fmaxf(deg[nb + n], 1.0f);
    }
    __syncthreads();

    float gj = lgl[lane], bj = lbl[lane];
    float accp = 0.f;
    int cur = bat[nb + w * 16];
    for (int q = 0; q < 16; q++) {
        int n = w * 16 + q;
        float v = S.outL[n][lane];
        float mu = v;
#pragma unroll
        for (int msk = 32; msk > 0; msk >>= 1) mu += __shfl_xor(mu, msk);
        mu *= (1.f / 64.f);
        float d = v - mu;
        float var = d * d;
#pragma unroll
        for (int msk = 32; msk > 0; msk >>= 1) var += __shfl_xor(var, msk);
        var *= (1.f / 64.f);
        float ov = d * rsqrtf(var + LN_EPS) * gj + bj;
        float hn = leaky(ov) + h[(size_t)(nb + n) * 64 + lane];
        h[(size_t)(nb + n) * 64 + lane] = hn;
        if (last) {
            int b = bat[nb + n];
            if (b != cur) { atomicAdd(&pooled[cur * 64 + lane], accp); accp = 0.f; cur = b; }
            accp += hn;
        }
    }
    if (last) atomicAdd(&pooled[cur * 64 + lane], accp);
}

__device__ __forceinline__ void head_body(HeadSmem& S, const float* __restrict__ pooled,
        const int* __restrict__ bat,
        const float* pw1, const float* pb1, const float* pw2, const float* pb2,
        const float* pw3, const float* pb3, float* __restrict__ out, int t) {
    if (t < 32) S.cntL[t] = 0.f;
    __syncthreads();
    {
        const int4* bp4 = (const int4*)(bat + t * 64);
        int cur = bat[t * 64];
        float c = 0.f;
        for (int q = 0; q < 16; q++) {
            int4 b4 = bp4[q];
            int bs[4] = { b4.x, b4.y, b4.z, b4.w };
#pragma unroll
            for (int e = 0; e < 4; e++) {
                if (bs[e] != cur) { atomicAdd(&S.cntL[cur], c); cur = bs[e]; c = 0.f; }
                c += 1.f;
            }
        }
        atomicAdd(&S.cntL[cur], c);
    }
    __syncthreads();
    for (int idx = t; idx < 2048; idx += 256) {
        int b = idx >> 6, j = idx & 63;
        S.ps[b][j] = pooled[idx] / fmaxf(S.cntL[b], 1.0f);
    }
    __syncthreads();
    for (int idx = t; idx < 2048; idx += 256) {
        int b = idx >> 6, j = idx & 63;
        float v = pb1[j];
#pragma unroll 8
        for (int i = 0; i < 64; i++) v += S.ps[b][i] * pw1[j * 64 + i];
        S.p1[b][j] = leaky(v);
    }
    __syncthreads();
    for (int idx = t; idx < 1024; idx += 256) {
        int b = idx >> 5, j = idx & 31;
        float v = pb2[j];
#pragma unroll 8
        for (int i = 0; i < 64; i++) v += S.p1[b][i] * pw2[j * 64 + i];
        S.p2[b][j] = leaky(v);
    }
    __syncthreads();
    if (t < 32) {
        float v = pb3[0];
#pragma unroll 8
        for (int i = 0; i < 32; i++) v += S.p2[t][i] * pw3[i];
        out[t] = v;
    }
}

// ================================================================ cooperative mega-kernel (grid 256)
__global__ __launch_bounds__(256, 1) void k_all(Params P) {
    __shared__ AllSmem smem;
    cg::grid_group grid = cg::this_grid();

    const int t    = threadIdx.x;
    const int bid  = blockIdx.x;
    const int lane = t & 63;
    const int w    = t >> 6;
    const int m    = lane & 31;
    const int kp   = lane >> 5;

    float* ws     = P.ws;
    float* h      = ws;
    float* agg    = ws + 1048576;
    float* deg    = ws + 4194304;
    float* pooled = ws + 4210688;
    f16*   Bp     = (f16*)(ws + 4212800);
    const int* srcp = P.eidx;
    const int* dstp = P.eidx + N_EDGES;

    // phase S: inproj + degree + Bp prep (zeroing done by host memset)
    {
        int base = bid * 4096;
#pragma unroll
        for (int q = 0; q < 16; q++) {
            int idx = base + q * 256 + t;
            int n = idx >> 6, j = idx & 63;
            const float* xr = P.x + n * 4;
            const float* wr = P.Win + j * 4;
            float v = P.bin[j] + xr[0] * wr[0] + xr[1] * wr[1] + xr[2] * wr[2] + xr[3] * wr[3];
            h[idx] = leaky(v);
        }
        atomicAdd(&deg[dstp[bid * 256 + t]], 1.0f);
        for (int gslot = bid * 4 + w; gslot < 1560; gslot += 1024) {
            int l     = gslot / 520;
            int slot  = gslot - l * 520;
            const float* ew3l = P.ew3 + (size_t)l * 262144;
            const float* eb3l = P.eb3 + (size_t)l * 4096;
            int i   = slot >> 3;
            int rem = slot & 7;
            int ks  = rem >> 1;
            int oq  = rem & 1;
            int o   = oq * 32 + m;
            int k0  = ks * 16 + kp * 8;
            float v[8];
            if (i < 64) {
                const float* s = ew3l + ((size_t)(i * 64 + o)) * 64 + k0;
                float4 a = ((const float4*)s)[0];
                float4 b = ((const float4*)s)[1];
                v[0] = a.x; v[1] = a.y; v[2] = a.z; v[3] = a.w;
                v[4] = b.x; v[5] = b.y; v[6] = b.z; v[7] = b.w;
            } else {
#pragma unroll
                for (int j = 0; j < 8; j++) v[j] = eb3l[(k0 + j) * 64 + o];
            }
            union { int4 i4; f16 a[8]; } outw;
#pragma unroll
            for (int j = 0; j < 8; j++) outw.a[j] = (f16)v[j];
            *(int4*)(Bp + (size_t)l * 266240 + (size_t)slot * 512 + lane * 8) = outw.i4;
        }
    }
    grid.sync();

    for (int l = 0; l < NLAYERS; l++) {
        float* agg_l = agg + (size_t)l * 1048576;
        msg_body(smem.m, h, P.ea, P.ew1 + l * 320, P.eb1 + l * 64,
                 P.ew2 + l * 4096, P.eb2 + l * 64,
                 Bp + (size_t)l * 266240, srcp, dstp, agg_l, bid * 256, t);
        grid.sync();
        node_body(smem.n, h, agg_l, deg, P.rw + l * 4096, P.rb + l * 64,
                  P.lg + l * 64, P.lb + l * 64, P.bat, pooled,
                  (l == NLAYERS - 1) ? 1 : 0, bid * 64, t);
        grid.sync();
    }

    if (bid == 0)
        head_body(smem.hd, pooled, P.bat, P.pw1, P.pb1, P.pw2, P.pb2, P.pw3, P.pb3, P.out, t);
}

// ================================================================ fallback kernels (multi-dispatch)
__global__ __launch_bounds__(256) void k_setup(const float* __restrict__ x,
                                               const float* __restrict__ Win,
                                               const float* __restrict__ bin,
                                               const int* __restrict__ dst,
                                               const float* __restrict__ ew3,
                                               const float* __restrict__ eb3,
                                               float* __restrict__ h,
                                               float* __restrict__ deg,
                                               f16* __restrict__ Bp) {
    int bid = blockIdx.x;
    if (bid < 4096) {
        int t = bid * 256 + threadIdx.x;
        int n = t >> 6, j = t & 63;
        const float* xr = x + n * 4;
        const float* wr = Win + j * 4;
        float v = bin[j] + xr[0] * wr[0] + xr[1] * wr[1] + xr[2] * wr[2] + xr[3] * wr[3];
        h[t] = leaky(v);
    } else if (bid < 4352) {
        int e = (bid - 4096) * 256 + threadIdx.x;
        atomicAdd(&deg[dst[e]], 1.0f);
    } else {
        int tg    = (bid - 4352) * 256 + threadIdx.x;
        int lane  = tg & 63;
        int gslot = tg >> 6;
        int l     = gslot / 520;
        int slot  = gslot - l * 520;
        const float* ew3l = ew3 + (size_t)l * 262144;
        const float* eb3l = eb3 + (size_t)l * 4096;
        int i   = slot >> 3;
        int rem = slot & 7;
        int ks  = rem >> 1;
        int oq  = rem & 1;
        int o   = oq * 32 + (lane & 31);
        int k0  = ks * 16 + (lane >> 5) * 8;
        float v[8];
        if (i < 64) {
            const float* s = ew3l + ((size_t)(i * 64 + o)) * 64 + k0;
            float4 a = ((const float4*)s)[0];
            float4 b = ((const float4*)s)[1];
            v[0] = a.x; v[1] = a.y; v[2] = a.z; v[3] = a.w;
            v[4] = b.x; v[5] = b.y; v[6] = b.z; v[7] = b.w;
        } else {
#pragma unroll
            for (int j = 0; j < 8; j++) v[j] = eb3l[(k0 + j) * 64 + o];
        }
        union { int4 i4; f16 a[8]; } outw;
#pragma unroll
        for (int j = 0; j < 8; j++) outw.a[j] = (f16)v[j];
        *(int4*)(Bp + (size_t)l * 266240 + (size_t)slot * 512 + lane * 8) = outw.i4;
    }
}

__global__ __launch_bounds__(256, 1) void k_msg_s(const float* __restrict__ h,
                                                  const float* __restrict__ ea,
                                                  const float* __restrict__ w1,
                                                  const float* __restrict__ b1,
                                                  const float* __restrict__ w2,
                                                  const float* __restrict__ b2,
                                                  const f16* __restrict__ Bp,
                                                  const int* __restrict__ src,
                                                  const int* __restrict__ dst,
                                                  float* __restrict__ agg) {
    __shared__ MsgSmem S;
    msg_body(S, h, ea, w1, b1, w2, b2, Bp, src, dst, agg, blockIdx.x * 256, threadIdx.x);
}

__global__ __launch_bounds__(256) void k_node_s(const float* __restrict__ agg,
                                                const float* __restrict__ deg,
                                                const float* __restrict__ rw,
                                                const float* __restrict__ rb,
                                                const float* __restrict__ lg,
                                                const float* __restrict__ lb,
                                                float* __restrict__ h,
                                                const int* __restrict__ batch,
                                                float* __restrict__ pooled,
                                                int last) {
    __shared__ NodeSmem S;
    node_body(S, h, agg, deg, rw, rb, lg, lb, batch, pooled, last, blockIdx.x * 64, threadIdx.x);
}

__global__ __launch_bounds__(256) void k_head_s(const float* __restrict__ pooled,
                                                const int* __restrict__ batch,
                                                const float* __restrict__ pw1, const float* __restrict__ pb1,
                                                const float* __restrict__ pw2, const float* __restrict__ pb2,
                                                const float* __restrict__ pw3, const float* __restrict__ pb3,
                                                float* __restrict__ out) {
    __shared__ HeadSmem S;
    head_body(S, pooled, batch, pw1, pb1, pw2, pb2, pw3, pb3, out, threadIdx.x);
}

// ----------------------------------------------------------------
extern "C" void kernel_launch(void* const* d_in, const int* in_sizes, int n_in,
                              void* d_out, int out_size, void* d_ws, size_t ws_size,
                              hipStream_t stream) {
    Params hp;
    hp.x    = (const float*)d_in[0];
    hp.eidx = (const int*)  d_in[1];
    hp.ea   = (const float*)d_in[2];
    hp.bat  = (const int*)  d_in[3];
    hp.Win  = (const float*)d_in[4];
    hp.bin  = (const float*)d_in[5];
    hp.ew1  = (const float*)d_in[6];
    hp.eb1  = (const float*)d_in[7];
    hp.ew2  = (const float*)d_in[8];
    hp.eb2  = (const float*)d_in[9];
    hp.ew3  = (const float*)d_in[10];
    hp.eb3  = (const float*)d_in[11];
    hp.rw   = (const float*)d_in[12];
    hp.rb   = (const float*)d_in[13];
    hp.lg   = (const float*)d_in[14];
    hp.lb   = (const float*)d_in[15];
    hp.pw1  = (const float*)d_in[16];
    hp.pb1  = (const float*)d_in[17];
    hp.pw2  = (const float*)d_in[18];
    hp.pb2  = (const float*)d_in[19];
    hp.pw3  = (const float*)d_in[20];
    hp.pb3  = (const float*)d_in[21];
    hp.out  = (float*)d_out;
    hp.ws   = (float*)d_ws;

    float* ws  = (float*)d_ws;
    float* agg = ws + 1048576;
    // zero agg[3] + deg + pooled (contiguous) via DMA, then one coop dispatch
    (void)hipMemsetAsync(agg, 0, (size_t)3164224 * sizeof(float), stream);

    void* args[] = { (void*)&hp };
    hipError_t err = hipLaunchCooperativeKernel(reinterpret_cast<void*>(k_all),
                                                dim3(256), dim3(256), args, 0, stream);
    if (err != hipSuccess) {
        // fallback: proven multi-dispatch path (bit-identical math)
        float* h      = ws;
        float* deg    = ws + 4194304;
        float* pooled = ws + 4210688;
        f16*   Bp     = (f16*)(ws + 4212800);
        const int* srcp = (const int*)d_in[1];
        const int* dstp = srcp + N_EDGES;

        k_setup<<<4742, 256, 0, stream>>>(hp.x, hp.Win, hp.bin, dstp, hp.ew3, hp.eb3, h, deg, Bp);
        for (int l = 0; l < NLAYERS; l++) {
            float* agg_l = agg + (size_t)l * 1048576;
            k_msg_s <<<N_EDGES / 256, 256, 0, stream>>>(h, hp.ea, hp.ew1 + l * 320, hp.eb1 + l * 64,
                                                        hp.ew2 + l * 4096, hp.eb2 + l * 64,
                                                        Bp + (size_t)l * 266240, srcp, dstp, agg_l);
            k_node_s<<<N_NODES / 64, 256, 0, stream>>>(agg_l, deg, hp.rw + l * 4096, hp.rb + l * 64,
                                                       hp.lg + l * 64, hp.lb + l * 64, h,
                                                       hp.bat, pooled, l == NLAYERS - 1 ? 1 : 0);
        }
        k_head_s<<<1, 256, 0, stream>>>(pooled, hp.bat, hp.pw1, hp.pb1, hp.pw2, hp.pb2,
                                        hp.pw3, hp.pb3, (float*)d_out);
    }
}